// Round 7
// baseline (154.150 us; speedup 1.0000x reference)
//
#include <hip/hip_runtime.h>

// ForwardKinematics, fp32: rotations (B,24,4) wxyz + positions (B,24,3)
// -> global joint positions (B,24,3). Fixed SMPL tree.
//
// Round 7: fully dense memory pipeline.
//   A: dense float4 global loads -> XOR-swizzled LDS transpose
//      (pitch 24 granules(16B)/sample; granule j stored at j^(s&7):
//       keeps 16B alignment AND bank-conflict-freedom both phases)
//   B: per-sample compute from LDS (ds_read_b128), wave-uniform 2-way
//      tree split (w0: joints 0..11; w1: 12..23 + re-derived spine)
//   C: outputs into the rot LDS region (reused after barrier)
//   D: dense float4 global stores (proven in round 6: WRITE == ideal)
// SPB=64 samples/block, 128 threads, LDS 48KB -> 3 blocks/CU.

typedef float f32x4 __attribute__((ext_vector_type(4)));

struct M { float r0,r1,r2,r3,r4,r5,r6,r7,r8,tx,ty,tz; };

__device__ __forceinline__ M loc(f32x4 q, float px, float py, float pz) {
    float inv = rsqrtf(q.x*q.x + q.y*q.y + q.z*q.z + q.w*q.w);
    float qw = q.x*inv, qx = q.y*inv, qy = q.z*inv, qz = q.w*inv;
    float x2 = qx+qx, y2 = qy+qy, z2 = qz+qz;
    float xx = qx*x2, yy = qy*y2, zz = qz*z2;
    float xy = qx*y2, yz = qy*z2, xz = qx*z2;
    float wx = qw*x2, wy = qw*y2, wz = qw*z2;
    M m;
    m.r0 = 1.f-(yy+zz); m.r1 = xy-wz;       m.r2 = xz+wy;
    m.r3 = xy+wz;       m.r4 = 1.f-(xx+zz); m.r5 = yz-wx;
    m.r6 = xz-wy;       m.r7 = yz+wx;       m.r8 = 1.f-(xx+yy);
    m.tx = px; m.ty = py; m.tz = pz;
    return m;
}

__device__ __forceinline__ M mul(const M& a, const M& b) {
    M c;
    c.r0 = a.r0*b.r0 + a.r1*b.r3 + a.r2*b.r6;
    c.r1 = a.r0*b.r1 + a.r1*b.r4 + a.r2*b.r7;
    c.r2 = a.r0*b.r2 + a.r1*b.r5 + a.r2*b.r8;
    c.r3 = a.r3*b.r0 + a.r4*b.r3 + a.r5*b.r6;
    c.r4 = a.r3*b.r1 + a.r4*b.r4 + a.r5*b.r7;
    c.r5 = a.r3*b.r2 + a.r4*b.r5 + a.r5*b.r8;
    c.r6 = a.r6*b.r0 + a.r7*b.r3 + a.r8*b.r6;
    c.r7 = a.r6*b.r1 + a.r7*b.r4 + a.r8*b.r7;
    c.r8 = a.r6*b.r2 + a.r7*b.r5 + a.r8*b.r8;
    c.tx = a.r0*b.tx + a.r1*b.ty + a.r2*b.tz + a.tx;
    c.ty = a.r3*b.tx + a.r4*b.ty + a.r5*b.tz + a.ty;
    c.tz = a.r6*b.tx + a.r7*b.ty + a.r8*b.tz + a.tz;
    return c;
}

#define SPB 64   // samples per block; 128 threads = 2 waves (w0/w1 = tree halves)

__global__ __launch_bounds__(128) void fk_kernel(
    const f32x4* __restrict__ rot4,   // B*24 float4 (one quat per joint)
    const f32x4* __restrict__ pos4,   // B*18 float4
    f32x4*       __restrict__ out4,   // B*18 float4
    int B)
{
    __shared__ f32x4 ldsR[SPB * 24];   // 24 KB; also reused for outputs
    __shared__ f32x4 ldsP[SPB * 24];   // 24 KB (18 of 24 granules used)

    const int t = threadIdx.x;   // 0..127
    const int w = t >> 6;        // wave id = subtree group
    const int l = t & 63;        // local sample

    // ---- A: dense loads -> swizzled LDS ----
    const size_t rbase = (size_t)blockIdx.x * (SPB * 24);
    const size_t rlim  = (size_t)B * 24;
#pragma unroll
    for (int i = 0; i < 12; ++i) {                 // 1536 f4 / 128 thr
        const int F = i * 128 + t;
        const int s = F / 24, j = F % 24;
        f32x4 v = {0.f, 0.f, 0.f, 0.f};
        if (rbase + F < rlim) v = rot4[rbase + F];
        ldsR[s * 24 + (j ^ (s & 7))] = v;
    }
    const size_t pbase = (size_t)blockIdx.x * (SPB * 18);
    const size_t plim  = (size_t)B * 18;
#pragma unroll
    for (int i = 0; i < 9; ++i) {                  // 1152 f4 / 128 thr
        const int F = i * 128 + t;
        const int s = F / 18, j = F % 18;
        f32x4 v = {0.f, 0.f, 0.f, 0.f};
        if (pbase + F < plim) v = pos4[pbase + F];
        ldsP[s * 24 + (j ^ (s & 7))] = v;
    }
    __syncthreads();

    // ---- B: compute ----
    const int b = blockIdx.x * SPB + l;
    const bool act = (b < B);
    float o[36];
    if (act) {
        const int sw = l & 7;
        const f32x4* R = ldsR + l * 24;
        const f32x4* P = ldsP + l * 24;
        if (w == 0) {
            // joints 0..11; pos dwords 0..35 = granules 0..8
            float tl[36];
#pragma unroll
            for (int i = 0; i < 9; ++i) {
                f32x4 v = P[i ^ sw];
                tl[4*i]=v.x; tl[4*i+1]=v.y; tl[4*i+2]=v.z; tl[4*i+3]=v.w;
            }
            constexpr int PAR[12] = {-1, 0, 0, 0, 1, 2, 3, 4, 5, 6, 7, 8};
            M G[12];
            G[0] = loc(R[0 ^ sw], tl[0], tl[1], tl[2]);
#pragma unroll
            for (int j = 1; j < 12; ++j)
                G[j] = mul(G[PAR[j]], loc(R[j ^ sw], tl[3*j], tl[3*j+1], tl[3*j+2]));
#pragma unroll
            for (int j = 0; j < 12; ++j) {
                o[3*j]=G[j].tx; o[3*j+1]=G[j].ty; o[3*j+2]=G[j].tz;
            }
        } else {
            // joints 12..23; pos dwords 36..71 = granules 9..17
            float tc[36];
#pragma unroll
            for (int i = 0; i < 9; ++i) {
                f32x4 v = P[(9 + i) ^ sw];
                tc[4*i]=v.x; tc[4*i+1]=v.y; tc[4*i+2]=v.z; tc[4*i+3]=v.w;
            }
            // spine pos: dw{0,1,2}=g0; {9,10,11}=g2.yzw; {18,19,20}=g4.zw,g5.x;
            //            {27,28,29}=g6.w,g7.xy
            f32x4 pg0 = P[0 ^ sw], pg2 = P[2 ^ sw], pg4 = P[4 ^ sw],
                  pg5 = P[5 ^ sw], pg6 = P[6 ^ sw], pg7 = P[7 ^ sw];
            M G[16];
            G[0] = loc(R[0 ^ sw], pg0.x, pg0.y, pg0.z);
            G[1] = mul(G[0], loc(R[3 ^ sw], pg2.y, pg2.z, pg2.w));
            G[2] = mul(G[1], loc(R[6 ^ sw], pg4.z, pg4.w, pg5.x));
            G[3] = mul(G[2], loc(R[9 ^ sw], pg6.w, pg7.x, pg7.y));
            constexpr int PL[12] = {3,3,3, 4,5,6, 8,9,10, 11,12,13};
#pragma unroll
            for (int j = 0; j < 12; ++j)
                G[4+j] = mul(G[PL[j]],
                             loc(R[(12 + j) ^ sw], tc[3*j], tc[3*j+1], tc[3*j+2]));
#pragma unroll
            for (int j = 0; j < 12; ++j) {
                o[3*j]=G[4+j].tx; o[3*j+1]=G[4+j].ty; o[3*j+2]=G[4+j].tz;
            }
        }
    }
    __syncthreads();   // all LDS reads done before output overwrites ldsR

    // ---- C: outputs -> ldsR (granules 0..17 = sample's 72 output dwords) ----
    if (act) {
        const int sw = l & 7;
#pragma unroll
        for (int m = 0; m < 9; ++m) {
            f32x4 v = {o[4*m], o[4*m+1], o[4*m+2], o[4*m+3]};
            ldsR[l * 24 + ((w * 9 + m) ^ sw)] = v;
        }
    }
    __syncthreads();

    // ---- D: dense stores ----
    const size_t obase = (size_t)blockIdx.x * (SPB * 18);
    const size_t olim  = (size_t)B * 18;
#pragma unroll
    for (int i = 0; i < 9; ++i) {
        const int F = i * 128 + t;
        const int s = F / 18, j = F % 18;
        if (obase + F < olim)
            out4[obase + F] = ldsR[s * 24 + (j ^ (s & 7))];
    }
}

extern "C" void kernel_launch(void* const* d_in, const int* in_sizes, int n_in,
                              void* d_out, int out_size, void* d_ws, size_t ws_size,
                              hipStream_t stream) {
    const int B = out_size / 72;           // (B,24,3)
    const void* rot = nullptr;
    const void* pos = nullptr;
    for (int i = 0; i < n_in; ++i) {       // resolve by size, not order
        if      (in_sizes[i] == B * 96) rot = d_in[i];
        else if (in_sizes[i] == B * 72) pos = d_in[i];
    }
    if (!rot) rot = d_in[2];
    if (!pos) pos = d_in[1];

    const int grid = (B + SPB - 1) / SPB;  // 2048 blocks @ B=131072
    fk_kernel<<<grid, 128, 0, stream>>>(
        (const f32x4*)rot, (const f32x4*)pos, (f32x4*)d_out, B);
}